// Round 6
// baseline (366.082 us; speedup 1.0000x reference)
//
#include <hip/hip_runtime.h>

#define DIM 128

typedef __attribute__((ext_vector_type(8))) short bf16x8;
typedef __attribute__((ext_vector_type(4))) float f32x4;

// ---- ws layout (float offsets) ----
#define WS_B12    0        // 128
#define WS_C      128      // 128  c = W_c2 @ sum_eE
#define WS_SUMEE  256      // 128
#define WS_S      384      // 1
#define WS_ZB     416      // 64   Z buckets (atomic, 64-way)
#define WS_GEB    512      // 32*128 ge buckets (atomic, 32-way)
#define WS_CPK    4608     // 128*4 packed col consts {c, b12, wvc, 0}
#define WS_WBF    5120     // 32768 bf16: Wcat[n][k] (n<128: W_c1 row n, else W_c2)
#define WS_EEP    21504    // 128*1024 sum_eE partials
#define WS_SEP    152576   // 1024 S partials
#define WS_SP     153600   // N
#define WS_E      415744   // N
#define WS_WEXP   677888   // N
#define WS_EBF    940032   // N*128 bf16 (64 MiB), plain row-major

__device__ __forceinline__ unsigned short f2bf(float f) {
    union { float f; unsigned u; } v; v.f = f;
    unsigned r = v.u + 0x7fffu + ((v.u >> 16) & 1u);
    return (unsigned short)(r >> 16);
}

__device__ __forceinline__ float bfbits(unsigned u) {
    union { unsigned u; float f; } v; v.u = u;
    return v.f;
}

// ---------------- K1: weights->bf16, b12, zero atomic buckets ----------------
__global__ __launch_bounds__(256) void k1_init(const float* __restrict__ Wc1,
                                               const float* __restrict__ Wc2,
                                               const float* __restrict__ bc1,
                                               const float* __restrict__ bc2,
                                               float* __restrict__ ws) {
    int gid = blockIdx.x * 256 + threadIdx.x;
    unsigned short* wbf = (unsigned short*)(ws + WS_WBF);
    if (gid < 32768) {
        int n = gid >> 7, k = gid & 127;
        float v = (n < 128) ? Wc1[n * 128 + k] : Wc2[(n - 128) * 128 + k];
        wbf[gid] = f2bf(v);
    }
    if (gid < 4096) ws[WS_GEB + gid] = 0.f;
    if (gid < 128) ws[WS_B12 + gid] = bc1[gid] + bc2[gid];
    if (gid < 64) ws[WS_ZB + gid] = 0.f;
}

// ---------------- K2: one pass over E -> sp, e, partials, row-major bf16 E ----------------
// 1024 blocks x 256 threads; 256 rows/block; 16 lanes per row. No contended atomics.
__global__ __launch_bounds__(256) void k2_stats(const float* __restrict__ E,
                                                const float* __restrict__ v,
                                                const float* __restrict__ wpa,
                                                const float* __restrict__ bpa,
                                                float* __restrict__ ws) {
    __shared__ float red[16][128];
    __shared__ float redS[16];
    int t = threadIdx.x;
    int wave = t >> 6, lane = t & 63;
    int cl = lane & 15, rs = lane >> 4;
    int row0 = blockIdx.x * 256;
    const float4* E4 = (const float4*)E;
    unsigned short* ebf = (unsigned short*)(ws + WS_EBF);

    float4 va = ((const float4*)v)[cl];
    float4 vb = ((const float4*)v)[16 + cl];
    float4 pa = ((const float4*)wpa)[cl];
    float4 pb = ((const float4*)wpa)[16 + cl];
    float bias = bpa[0];

    float4 acc0 = {0.f, 0.f, 0.f, 0.f}, acc1 = {0.f, 0.f, 0.f, 0.f};
    float se = 0.f;
    float* sp_ws = ws + WS_SP;
    float* e_ws = ws + WS_E;

#pragma unroll 4
    for (int it = 0; it < 16; ++it) {
        int row = row0 + it * 16 + wave * 4 + rs;
        float4 x0 = E4[row * 32 + cl];
        float4 x1 = E4[row * 32 + 16 + cl];
        unsigned p0 = (unsigned)f2bf(x0.x) | ((unsigned)f2bf(x0.y) << 16);
        unsigned p1 = (unsigned)f2bf(x0.z) | ((unsigned)f2bf(x0.w) << 16);
        unsigned p2 = (unsigned)f2bf(x1.x) | ((unsigned)f2bf(x1.y) << 16);
        unsigned p3 = (unsigned)f2bf(x1.z) | ((unsigned)f2bf(x1.w) << 16);
        unsigned short* er = ebf + (size_t)row * 128;
        *(uint2*)(er + cl * 4) = make_uint2(p0, p1);
        *(uint2*)(er + 64 + cl * 4) = make_uint2(p2, p3);

        float dv = x0.x * va.x + x0.y * va.y + x0.z * va.z + x0.w * va.w
                 + x1.x * vb.x + x1.y * vb.y + x1.z * vb.z + x1.w * vb.w;
        float dp = x0.x * pa.x + x0.y * pa.y + x0.z * pa.z + x0.w * pa.w
                 + x1.x * pb.x + x1.y * pb.y + x1.z * pb.z + x1.w * pb.w;
        for (int off = 1; off < 16; off <<= 1) {
            dv += __shfl_xor(dv, off);
            dp += __shfl_xor(dp, off);
        }
        float e = __expf(dp + bias);
        if (cl == 0) {
            sp_ws[row] = dv;
            e_ws[row] = e;
            se += e;
        }
        acc0.x += e * x0.x; acc0.y += e * x0.y; acc0.z += e * x0.z; acc0.w += e * x0.w;
        acc1.x += e * x1.x; acc1.y += e * x1.y; acc1.z += e * x1.z; acc1.w += e * x1.w;
    }
    int rr = wave * 4 + rs;
    float* dst = red[rr];
    dst[cl * 4 + 0] = acc0.x; dst[cl * 4 + 1] = acc0.y;
    dst[cl * 4 + 2] = acc0.z; dst[cl * 4 + 3] = acc0.w;
    dst[64 + cl * 4 + 0] = acc1.x; dst[64 + cl * 4 + 1] = acc1.y;
    dst[64 + cl * 4 + 2] = acc1.z; dst[64 + cl * 4 + 3] = acc1.w;
    if (cl == 0) redS[rr] = se;
    __syncthreads();
    if (t < 128) {
        float s = 0.f;
#pragma unroll
        for (int r = 0; r < 16; ++r) s += red[r][t];
        ws[WS_EEP + t * 1024 + blockIdx.x] = s;
    }
    if (t == 0) {
        float s = 0.f;
#pragma unroll
        for (int r = 0; r < 16; ++r) s += redS[r];
        ws[WS_SEP + blockIdx.x] = s;
    }
}

// ---------------- K2b: reduce partials -> SUMEE[128], S ----------------
__global__ __launch_bounds__(256) void k2b_reduce(float* __restrict__ ws) {
    __shared__ float r4[4];
    int t = threadIdx.x, blk = blockIdx.x;
    const float* src = (blk < 128) ? (ws + WS_EEP + blk * 1024) : (ws + WS_SEP);
    float s = src[t] + src[t + 256] + src[t + 512] + src[t + 768];
    for (int off = 1; off < 64; off <<= 1) s += __shfl_xor(s, off);
    if ((t & 63) == 0) r4[t >> 6] = s;
    __syncthreads();
    if (t == 0) {
        float tot = r4[0] + r4[1] + r4[2] + r4[3];
        if (blk < 128) ws[WS_SUMEE + blk] = tot;
        else ws[WS_S] = tot;
    }
}

// ---------------- K3: c = W_c2 @ sum_eE + packed col consts ----------------
__global__ __launch_bounds__(128) void k3_c(const float* __restrict__ Wc2,
                                            const float* __restrict__ wvc,
                                            float* __restrict__ ws) {
    int j = threadIdx.x;
    const float4* row = (const float4*)(Wc2 + j * 128);
    const float4* se = (const float4*)(ws + WS_SUMEE);
    float4 s4 = {0.f, 0.f, 0.f, 0.f};
#pragma unroll
    for (int k = 0; k < 32; ++k) {
        float4 a = row[k], b = se[k];
        s4.x += a.x * b.x; s4.y += a.y * b.y; s4.z += a.z * b.z; s4.w += a.w * b.w;
    }
    float cj = s4.x + s4.y + s4.z + s4.w;
    ws[WS_C + j] = cj;
    *(float4*)(ws + WS_CPK + j * 4) = (float4){cj, ws[WS_B12 + j], wvc[j], 0.f};
}

// ---------------- K4: wave-private MFMA GEMM + fused epilogue ----------------
// 4096 blocks x 256 threads (4 waves); wave w owns rows [blk*64+16w, +16).
// A-frags load directly from row-major bf16 ebf (zero redundancy, no staging,
// no barrier until the tiny ge/Z combine tail). pi is wave-private.
__global__ __launch_bounds__(256, 4) void k4_main(const float* __restrict__ bvc_p,
                                                  float* __restrict__ ws) {
    __shared__ float gep[4][128];
    __shared__ float zw[4];

    int t = threadIdx.x;
    int w = t >> 6, lane = t & 63, cl = lane & 15, q = lane >> 4;
    int row0 = blockIdx.x * 64 + w * 16;          // this wave's 16 rows
    const unsigned short* ebf = (const unsigned short*)(ws + WS_EBF);
    const unsigned short* wbf = (const unsigned short*)(ws + WS_WBF);

    // A fragments: lane holds row row0+cl, k = kt*32 + q*8 .. +8
    const unsigned short* arow = ebf + (size_t)(row0 + cl) * 128;
    bf16x8 a[4];
#pragma unroll
    for (int kt = 0; kt < 4; ++kt)
        a[kt] = *(const bf16x8*)(arow + kt * 32 + q * 8);

    // row constants for this lane's epilogue rows q*4..q*4+4 (broadcast float4)
    float4 sp4 = *(const float4*)(ws + WS_SP + row0 + q * 4);
    float4 e4  = *(const float4*)(ws + WS_E + row0 + q * 4);
    float Sv = ws[WS_S];
    float bvc = bvc_p[0];
    float dinv[4];
#pragma unroll
    for (int r = 0; r < 4; ++r) dinv[r] = 1.0f / (Sv - ((const float*)&e4)[r]);

    // pair loop over 8 column-tiles (u1: ct=p, u2: ct=p+8)
    float pirow[4] = {0.f, 0.f, 0.f, 0.f};
#pragma unroll 2
    for (int p = 0; p < 8; ++p) {
        int j = p * 16 + cl;
        float4 cc = *(const float4*)(ws + WS_CPK + j * 4);   // {c, b12, wvc, 0}
        bf16x8 b0[4], b1[4];
#pragma unroll
        for (int kt = 0; kt < 4; ++kt) {
            b0[kt] = *(const bf16x8*)(wbf + (size_t)j * 128 + kt * 32 + q * 8);
            b1[kt] = *(const bf16x8*)(wbf + (size_t)(128 + j) * 128 + kt * 32 + q * 8);
        }
        f32x4 acc0 = {0.f, 0.f, 0.f, 0.f}, acc1 = {0.f, 0.f, 0.f, 0.f};
#pragma unroll
        for (int kt = 0; kt < 4; ++kt) {
            acc0 = __builtin_amdgcn_mfma_f32_16x16x32_bf16(a[kt], b0[kt], acc0, 0, 0, 0);
            acc1 = __builtin_amdgcn_mfma_f32_16x16x32_bf16(a[kt], b1[kt], acc1, 0, 0, 0);
        }
#pragma unroll
        for (int reg = 0; reg < 4; ++reg) {
            float er = ((const float*)&e4)[reg];
            float h = acc0[reg] + cc.y + (cc.x - er * acc1[reg]) * dinv[reg];
            pirow[reg] += cc.z * fmaxf(h, 0.f);
        }
    }
    // close pi over the 16 col-lanes
#pragma unroll
    for (int reg = 0; reg < 4; ++reg) {
        pirow[reg] += __shfl_xor(pirow[reg], 1);
        pirow[reg] += __shfl_xor(pirow[reg], 2);
        pirow[reg] += __shfl_xor(pirow[reg], 4);
        pirow[reg] += __shfl_xor(pirow[reg], 8);
    }

    // wexp for rows q*4+reg (cl-redundant), write + Z
    float4 we4;
#pragma unroll
    for (int reg = 0; reg < 4; ++reg)
        ((float*)&we4)[reg] = __expf(((const float*)&sp4)[reg] + bvc + pirow[reg]);
    if (cl == 0) *(float4*)(ws + WS_WEXP + row0 + q * 4) = we4;
    float z = we4.x + we4.y + we4.z + we4.w;
    z += __shfl_xor(z, 16);
    z += __shfl_xor(z, 32);
    if (lane == 0) zw[w] = z;

    // ge partials: lane covers cols [cl*8,cl*8+8) of rows q*4..+4 (L1-hot re-read)
    float acc8[8] = {0.f, 0.f, 0.f, 0.f, 0.f, 0.f, 0.f, 0.f};
#pragma unroll
    for (int reg = 0; reg < 4; ++reg) {
        float wer = ((const float*)&we4)[reg];
        uint4 u = *(const uint4*)(ebf + (size_t)(row0 + q * 4 + reg) * 128 + cl * 8);
        acc8[0] += wer * bfbits(u.x << 16);
        acc8[1] += wer * bfbits(u.x & 0xffff0000u);
        acc8[2] += wer * bfbits(u.y << 16);
        acc8[3] += wer * bfbits(u.y & 0xffff0000u);
        acc8[4] += wer * bfbits(u.z << 16);
        acc8[5] += wer * bfbits(u.z & 0xffff0000u);
        acc8[6] += wer * bfbits(u.w << 16);
        acc8[7] += wer * bfbits(u.w & 0xffff0000u);
    }
#pragma unroll
    for (int jj = 0; jj < 8; ++jj) {
        acc8[jj] += __shfl_xor(acc8[jj], 16);
        acc8[jj] += __shfl_xor(acc8[jj], 32);
    }
    if (lane < 16) {
        *(float4*)&gep[w][cl * 8] = (float4){acc8[0], acc8[1], acc8[2], acc8[3]};
        *(float4*)&gep[w][cl * 8 + 4] = (float4){acc8[4], acc8[5], acc8[6], acc8[7]};
    }
    __syncthreads();

    if (t < 128) {
        float tot = gep[0][t] + gep[1][t] + gep[2][t] + gep[3][t];
        atomicAdd(&ws[WS_GEB + (blockIdx.x & 31) * 128 + t], tot);   // 128 adds/address
    }
    if (t == 128) {
        float zs = zw[0] + zw[1] + zw[2] + zw[3];
        atomicAdd(&ws[WS_ZB + (blockIdx.x & 63)], zs);               // 64 adds/address
    }
}

// ---------------- K5: normalize + write outputs ----------------
__global__ __launch_bounds__(256) void k5_final(const float* __restrict__ ws,
                                                float* __restrict__ out) {
    int t = threadIdx.x, blk = blockIdx.x;
    float z = ws[WS_ZB + (t & 63)];
    for (int off = 1; off < 64; off <<= 1) z += __shfl_xor(z, off);
    float invZ = 1.0f / z;
    if (blk < 1024) {
        int i = blk * 256 + t;
        out[128 + i] = ws[WS_WEXP + i] * invZ;
    } else if (t < 128) {
        float s = 0.f;
#pragma unroll
        for (int b = 0; b < 32; ++b) s += ws[WS_GEB + b * 128 + t];
        out[t] = s * invZ;
    }
}

extern "C" void kernel_launch(void* const* d_in, const int* in_sizes, int n_in,
                              void* d_out, int out_size, void* d_ws, size_t ws_size,
                              hipStream_t stream) {
    const float* E   = (const float*)d_in[0];
    const float* v   = (const float*)d_in[1];
    const float* Wc1 = (const float*)d_in[2];
    const float* bc1 = (const float*)d_in[3];
    const float* Wc2 = (const float*)d_in[4];
    const float* bc2 = (const float*)d_in[5];
    const float* wpa = (const float*)d_in[6];
    const float* bpa = (const float*)d_in[7];
    const float* wvc = (const float*)d_in[8];
    const float* bvc = (const float*)d_in[9];
    float* ws  = (float*)d_ws;
    float* out = (float*)d_out;

    k1_init<<<128, 256, 0, stream>>>(Wc1, Wc2, bc1, bc2, ws);
    k2_stats<<<1024, 256, 0, stream>>>(E, v, wpa, bpa, ws);
    k2b_reduce<<<129, 256, 0, stream>>>(ws);
    k3_c<<<1, 128, 0, stream>>>(Wc2, wvc, ws);
    k4_main<<<4096, 256, 0, stream>>>(bvc, ws);
    k5_final<<<1025, 256, 0, stream>>>(ws, out);
}

// Round 7
// 310.315 us; speedup vs baseline: 1.1797x; 1.1797x over previous
//
#include <hip/hip_runtime.h>

typedef __attribute__((ext_vector_type(8))) short bf16x8;
typedef __attribute__((ext_vector_type(4))) float f32x4;

// ---- ws layout (float offsets) ----
#define WS_B12    0        // 128
#define WS_CPK    128      // 128*4 packed col consts {c, b12, wvc, 0}
#define WS_SUMEE  640      // 128
#define WS_S      768      // 1
#define WS_ZB     800      // 64  Z buckets (atomic, 64-way)
#define WS_WBF    896      // 16384 floats = 32768 bf16: Wcat[n][k]
#define WS_EEP    17280    // 128*2048 sum_eE partials [d*2048+blk]
#define WS_SEP    279424   // 2048 S partials
#define WS_SP     281472   // N
#define WS_E      543616   // N
#define WS_WEXP   805760   // N
#define WS_GOUT   1067904  // 8192*128 per-block ge partials (plain stores)
#define WS_G2     2116480  // 256*128 stage-2 ge partials

__device__ __forceinline__ unsigned f2bf(float f) {
    union { float f; unsigned u; } v; v.f = f;
    unsigned r = v.u + 0x7fffu + ((v.u >> 16) & 1u);
    return r >> 16;
}

__device__ __forceinline__ float bfbits(unsigned u) {
    union { unsigned u; float f; } v; v.u = u;
    return v.f;
}

// ---------------- K1: weights->bf16, b12, zero Z buckets ----------------
__global__ __launch_bounds__(256) void k1_init(const float* __restrict__ Wc1,
                                               const float* __restrict__ Wc2,
                                               const float* __restrict__ bc1,
                                               const float* __restrict__ bc2,
                                               float* __restrict__ ws) {
    int gid = blockIdx.x * 256 + threadIdx.x;
    unsigned short* wbf = (unsigned short*)(ws + WS_WBF);
    if (gid < 32768) {
        int n = gid >> 7, k = gid & 127;
        float v = (n < 128) ? Wc1[n * 128 + k] : Wc2[(n - 128) * 128 + k];
        wbf[gid] = (unsigned short)f2bf(v);
    }
    if (gid < 128) ws[WS_B12 + gid] = bc1[gid] + bc2[gid];
    if (gid < 64) ws[WS_ZB + gid] = 0.f;
}

// ---------------- K2: one pass over E -> sp, e, per-block {S, sum_eE} partials ----------------
// 2048 blocks x 256 threads; 128 rows/block; 16 lanes per row. No contended atomics, no ebf.
__global__ __launch_bounds__(256) void k2_stats(const float* __restrict__ E,
                                                const float* __restrict__ v,
                                                const float* __restrict__ wpa,
                                                const float* __restrict__ bpa,
                                                float* __restrict__ ws) {
    __shared__ float red[16][128];
    __shared__ float redS[16];
    int t = threadIdx.x;
    int wave = t >> 6, lane = t & 63;
    int cl = lane & 15, rs = lane >> 4;
    int row0 = blockIdx.x * 128;
    const float4* E4 = (const float4*)E;

    float4 va = ((const float4*)v)[cl];
    float4 vb = ((const float4*)v)[16 + cl];
    float4 pa = ((const float4*)wpa)[cl];
    float4 pb = ((const float4*)wpa)[16 + cl];
    float bias = bpa[0];

    float4 acc0 = {0.f, 0.f, 0.f, 0.f}, acc1 = {0.f, 0.f, 0.f, 0.f};
    float se = 0.f;
    float* sp_ws = ws + WS_SP;
    float* e_ws = ws + WS_E;

#pragma unroll 4
    for (int it = 0; it < 8; ++it) {
        int row = row0 + it * 16 + wave * 4 + rs;
        float4 x0 = E4[row * 32 + cl];
        float4 x1 = E4[row * 32 + 16 + cl];
        float dv = x0.x * va.x + x0.y * va.y + x0.z * va.z + x0.w * va.w
                 + x1.x * vb.x + x1.y * vb.y + x1.z * vb.z + x1.w * vb.w;
        float dp = x0.x * pa.x + x0.y * pa.y + x0.z * pa.z + x0.w * pa.w
                 + x1.x * pb.x + x1.y * pb.y + x1.z * pb.z + x1.w * pb.w;
        for (int off = 1; off < 16; off <<= 1) {
            dv += __shfl_xor(dv, off);
            dp += __shfl_xor(dp, off);
        }
        float e = __expf(dp + bias);
        if (cl == 0) {
            sp_ws[row] = dv;
            e_ws[row] = e;
            se += e;
        }
        acc0.x += e * x0.x; acc0.y += e * x0.y; acc0.z += e * x0.z; acc0.w += e * x0.w;
        acc1.x += e * x1.x; acc1.y += e * x1.y; acc1.z += e * x1.z; acc1.w += e * x1.w;
    }
    int rr = wave * 4 + rs;
    float* dst = red[rr];
    dst[cl * 4 + 0] = acc0.x; dst[cl * 4 + 1] = acc0.y;
    dst[cl * 4 + 2] = acc0.z; dst[cl * 4 + 3] = acc0.w;
    dst[64 + cl * 4 + 0] = acc1.x; dst[64 + cl * 4 + 1] = acc1.y;
    dst[64 + cl * 4 + 2] = acc1.z; dst[64 + cl * 4 + 3] = acc1.w;
    if (cl == 0) redS[rr] = se;
    __syncthreads();
    if (t < 128) {
        float s = 0.f;
#pragma unroll
        for (int r = 0; r < 16; ++r) s += red[r][t];
        ws[WS_EEP + t * 2048 + blockIdx.x] = s;
    }
    if (t == 0) {
        float s = 0.f;
#pragma unroll
        for (int r = 0; r < 16; ++r) s += redS[r];
        ws[WS_SEP + blockIdx.x] = s;
    }
}

// ---------------- K2b: reduce partials -> SUMEE[128], S ----------------
__global__ __launch_bounds__(256) void k2b_reduce(float* __restrict__ ws) {
    __shared__ float r4[4];
    int t = threadIdx.x, blk = blockIdx.x;
    const float* src = (blk < 128) ? (ws + WS_EEP + blk * 2048) : (ws + WS_SEP);
    float s = 0.f;
#pragma unroll
    for (int k = 0; k < 8; ++k) s += src[t + 256 * k];
    for (int off = 1; off < 64; off <<= 1) s += __shfl_xor(s, off);
    if ((t & 63) == 0) r4[t >> 6] = s;
    __syncthreads();
    if (t == 0) {
        float tot = r4[0] + r4[1] + r4[2] + r4[3];
        if (blk < 128) ws[WS_SUMEE + blk] = tot;
        else ws[WS_S] = tot;
    }
}

// ---------------- K3: c = W_c2 @ sum_eE + packed col consts ----------------
__global__ __launch_bounds__(128) void k3_c(const float* __restrict__ Wc2,
                                            const float* __restrict__ wvc,
                                            float* __restrict__ ws) {
    int j = threadIdx.x;
    const float4* row = (const float4*)(Wc2 + j * 128);
    const float4* se = (const float4*)(ws + WS_SUMEE);
    float4 s4 = {0.f, 0.f, 0.f, 0.f};
#pragma unroll
    for (int k = 0; k < 32; ++k) {
        float4 a = row[k], b = se[k];
        s4.x += a.x * b.x; s4.y += a.y * b.y; s4.z += a.z * b.z; s4.w += a.w * b.w;
    }
    float cj = s4.x + s4.y + s4.z + s4.w;
    *(float4*)(ws + WS_CPK + j * 4) = (float4){cj, ws[WS_B12 + j], wvc[j], 0.f};
}

// ---------------- K4: small-block MFMA GEMM + fused epilogue ----------------
// 8192 blocks x 256 threads (4 waves); 32 rows/block; swizzled bf16 LDS tile (8 KB).
// Wave w computes all 32 rows for col-pairs p=w and p=w+4 (32 MFMA/wave).
// ge partials plain-stored per block (no atomics); Z via 64-way buckets.
__global__ __launch_bounds__(256, 4) void k4_main(const float* __restrict__ E,
                                                  const float* __restrict__ bvc_p,
                                                  float* __restrict__ ws) {
    __shared__ unsigned short Elds[32 * 128];   // bf16, swizzled 16B chunks
    __shared__ float pim[4][32];
    __shared__ float gep[4][128];
    __shared__ float zw[4];

    int t = threadIdx.x;
    int w = t >> 6, lane = t & 63, cl = lane & 15, q = lane >> 4;
    int row0 = blockIdx.x * 32;
    const unsigned short* wbf = (const unsigned short*)(ws + WS_WBF);

    // stage: fp32 -> bf16, swizzle chunk c (16B) -> c ^ ((row&1)<<2)
    const float4* E4 = (const float4*)E + (size_t)row0 * 32;
#pragma unroll
    for (int i = 0; i < 4; ++i) {
        int idx = t + 256 * i;
        int row = idx >> 5, kq = idx & 31;          // kq: 8B unit within row
        float4 x = E4[idx];
        unsigned p0 = f2bf(x.x) | (f2bf(x.y) << 16);
        unsigned p1 = f2bf(x.z) | (f2bf(x.w) << 16);
        int cc = (kq >> 1) ^ ((row & 1) << 2);
        *(uint2*)&Elds[row * 128 + cc * 8 + (kq & 1) * 4] = make_uint2(p0, p1);
    }

    // row constants (L2-hot, overlap with staging latency)
    float Sv = ws[WS_S];
    float bvc = bvc_p[0];
    float4 eA = *(const float4*)(ws + WS_E + row0 + q * 4);        // rows q*4..+4
    float4 eB = *(const float4*)(ws + WS_E + row0 + 16 + q * 4);   // rows 16+q*4..+4
    float dinvA[4], dinvB[4];
#pragma unroll
    for (int r = 0; r < 4; ++r) {
        dinvA[r] = 1.0f / (Sv - ((const float*)&eA)[r]);
        dinvB[r] = 1.0f / (Sv - ((const float*)&eB)[r]);
    }
    int r0 = w * 8 + q * 2;                        // this lane's 2 rows (wexp/ge)
    float sp0 = ws[WS_SP + row0 + r0];
    float sp1 = ws[WS_SP + row0 + r0 + 1];
    __syncthreads();

    // A fragments from swizzled LDS (reused across both col-pairs)
    bf16x8 a[2][4];
#pragma unroll
    for (int rt = 0; rt < 2; ++rt) {
        int row = rt * 16 + cl;
        int sw = (row & 1) << 2;
        const unsigned short* rbase = Elds + row * 128;
#pragma unroll
        for (int kt = 0; kt < 4; ++kt)
            a[rt][kt] = *(const bf16x8*)(rbase + ((((kt << 2) + q) ^ sw) << 3));
    }

    float pirow[2][4] = {{0.f, 0.f, 0.f, 0.f}, {0.f, 0.f, 0.f, 0.f}};
#pragma unroll 1
    for (int pp = 0; pp < 2; ++pp) {
        int j = (w + pp * 4) * 16 + cl;
        float4 cc = *(const float4*)(ws + WS_CPK + j * 4);   // {c, b12, wvc, 0}
        bf16x8 b0[4], b1[4];
#pragma unroll
        for (int kt = 0; kt < 4; ++kt) {
            b0[kt] = *(const bf16x8*)(wbf + (size_t)j * 128 + kt * 32 + q * 8);
            b1[kt] = *(const bf16x8*)(wbf + (size_t)(128 + j) * 128 + kt * 32 + q * 8);
        }
#pragma unroll
        for (int rt = 0; rt < 2; ++rt) {
            f32x4 acc0 = {0.f, 0.f, 0.f, 0.f}, acc1 = {0.f, 0.f, 0.f, 0.f};
#pragma unroll
            for (int kt = 0; kt < 4; ++kt) {
                acc0 = __builtin_amdgcn_mfma_f32_16x16x32_bf16(a[rt][kt], b0[kt], acc0, 0, 0, 0);
                acc1 = __builtin_amdgcn_mfma_f32_16x16x32_bf16(a[rt][kt], b1[kt], acc1, 0, 0, 0);
            }
            const float* ee = rt ? (const float*)&eB : (const float*)&eA;
            const float* dd = rt ? dinvB : dinvA;
#pragma unroll
            for (int reg = 0; reg < 4; ++reg) {
                float h = acc0[reg] + cc.y + (cc.x - ee[reg] * acc1[reg]) * dd[reg];
                pirow[rt][reg] += cc.z * fmaxf(h, 0.f);
            }
        }
    }
    // close pi over 16 col-lanes; write per-wave partial
#pragma unroll
    for (int rt = 0; rt < 2; ++rt)
#pragma unroll
        for (int reg = 0; reg < 4; ++reg) {
            float p = pirow[rt][reg];
            p += __shfl_xor(p, 1);
            p += __shfl_xor(p, 2);
            p += __shfl_xor(p, 4);
            p += __shfl_xor(p, 8);
            if (cl == 0) pim[w][rt * 16 + q * 4 + reg] = p;
        }
    __syncthreads();

    // wexp for this lane's 2 rows (cl-redundant), Z, ge partials
    float pi0 = pim[0][r0] + pim[1][r0] + pim[2][r0] + pim[3][r0];
    float pi1 = pim[0][r0 + 1] + pim[1][r0 + 1] + pim[2][r0 + 1] + pim[3][r0 + 1];
    float we0 = __expf(sp0 + bvc + pi0);
    float we1 = __expf(sp1 + bvc + pi1);
    if (cl == 0) *(float2*)(ws + WS_WEXP + row0 + r0) = make_float2(we0, we1);
    float z = we0 + we1;
    z += __shfl_xor(z, 16);
    z += __shfl_xor(z, 32);
    if (lane == 0) zw[w] = z;

    float acc8[8] = {0.f, 0.f, 0.f, 0.f, 0.f, 0.f, 0.f, 0.f};
#pragma unroll
    for (int rr = 0; rr < 2; ++rr) {
        int r = r0 + rr;                            // r&1 == rr
        float wer = rr ? we1 : we0;
        int cc = cl ^ (rr << 2);
        uint4 u = *(const uint4*)(Elds + r * 128 + cc * 8);
        acc8[0] += wer * bfbits(u.x << 16);
        acc8[1] += wer * bfbits(u.x & 0xffff0000u);
        acc8[2] += wer * bfbits(u.y << 16);
        acc8[3] += wer * bfbits(u.y & 0xffff0000u);
        acc8[4] += wer * bfbits(u.z << 16);
        acc8[5] += wer * bfbits(u.z & 0xffff0000u);
        acc8[6] += wer * bfbits(u.w << 16);
        acc8[7] += wer * bfbits(u.w & 0xffff0000u);
    }
#pragma unroll
    for (int jj = 0; jj < 8; ++jj) {
        acc8[jj] += __shfl_xor(acc8[jj], 16);
        acc8[jj] += __shfl_xor(acc8[jj], 32);
    }
    if (lane < 16) {
        *(float4*)&gep[w][cl * 8] = (float4){acc8[0], acc8[1], acc8[2], acc8[3]};
        *(float4*)&gep[w][cl * 8 + 4] = (float4){acc8[4], acc8[5], acc8[6], acc8[7]};
    }
    __syncthreads();

    if (t < 128) {
        float tot = gep[0][t] + gep[1][t] + gep[2][t] + gep[3][t];
        ws[WS_GOUT + (size_t)blockIdx.x * 128 + t] = tot;        // plain store
    }
    if (t == 0)
        atomicAdd(&ws[WS_ZB + (blockIdx.x & 63)], zw[0] + zw[1] + zw[2] + zw[3]);
}

// ---------------- K4b: ge partial reduce stage 1 (8192 -> 256) ----------------
__global__ __launch_bounds__(128) void k4b_ge(float* __restrict__ ws) {
    int t = threadIdx.x, b = blockIdx.x;
    const float* src = ws + WS_GOUT + (size_t)b * 32 * 128;
    float s = 0.f;
#pragma unroll 8
    for (int k = 0; k < 32; ++k) s += src[k * 128 + t];
    ws[WS_G2 + b * 128 + t] = s;
}

// ---------------- K5: normalize + write outputs ----------------
__global__ __launch_bounds__(256) void k5_final(const float* __restrict__ ws,
                                                float* __restrict__ out) {
    int t = threadIdx.x, blk = blockIdx.x;
    float z = ws[WS_ZB + (t & 63)];
    for (int off = 1; off < 64; off <<= 1) z += __shfl_xor(z, off);
    float invZ = 1.0f / z;
    if (blk < 1024) {
        int i = blk * 256 + t;
        out[128 + i] = ws[WS_WEXP + i] * invZ;
    } else if (t < 128) {
        float s = 0.f;
#pragma unroll 8
        for (int k = 0; k < 256; ++k) s += ws[WS_G2 + k * 128 + t];
        out[t] = s * invZ;
    }
}

extern "C" void kernel_launch(void* const* d_in, const int* in_sizes, int n_in,
                              void* d_out, int out_size, void* d_ws, size_t ws_size,
                              hipStream_t stream) {
    const float* E   = (const float*)d_in[0];
    const float* v   = (const float*)d_in[1];
    const float* Wc1 = (const float*)d_in[2];
    const float* bc1 = (const float*)d_in[3];
    const float* Wc2 = (const float*)d_in[4];
    const float* bc2 = (const float*)d_in[5];
    const float* wpa = (const float*)d_in[6];
    const float* bpa = (const float*)d_in[7];
    const float* wvc = (const float*)d_in[8];
    const float* bvc = (const float*)d_in[9];
    float* ws  = (float*)d_ws;
    float* out = (float*)d_out;

    k1_init<<<128, 256, 0, stream>>>(Wc1, Wc2, bc1, bc2, ws);
    k2_stats<<<2048, 256, 0, stream>>>(E, v, wpa, bpa, ws);
    k2b_reduce<<<129, 256, 0, stream>>>(ws);
    k3_c<<<1, 128, 0, stream>>>(Wc2, wvc, ws);
    k4_main<<<8192, 256, 0, stream>>>(E, bvc, ws);
    k4b_ge<<<256, 128, 0, stream>>>(ws);
    k5_final<<<1025, 256, 0, stream>>>(ws, out);
}